// Round 12
// baseline (294.209 us; speedup 1.0000x reference)
//
#include <hip/hip_runtime.h>
#include <cmath>

typedef unsigned short u16;
typedef unsigned int u32;
typedef __bf16 bf16x8 __attribute__((ext_vector_type(8)));
typedef float  floatx4 __attribute__((ext_vector_type(4)));
typedef float  floatx16 __attribute__((ext_vector_type(16)));
typedef unsigned int u32x4 __attribute__((ext_vector_type(4)));

#define T_DIM 2048
#define E_DIM 1024
#define H_DIM 16
#define HD    64
#define M_DIM 8192                    // B*T
#define NE    8388608                 // M*E  (also B*H*T*HD)
#define E2    1048576                 // E*E
#define QSCALE 0.18033688f            // 0.125 * log2(e): logits in exp2 domain

// float -> bf16 (RNE)
__device__ __forceinline__ u16 f2bf(float f) {
    unsigned u = __builtin_bit_cast(unsigned, f);
    return (u16)((u + 0x7FFFu + ((u >> 16) & 1u)) >> 16);
}
// two floats -> packed bf16x2 (proven numerics)
__device__ __forceinline__ u32 pack2bf(float f0, float f1) {
    u32 a0 = __builtin_bit_cast(u32, f0) + 0x8000u;
    u32 a1 = __builtin_bit_cast(u32, f1) + 0x8000u;
    return __builtin_amdgcn_perm(a1, a0, 0x07060302u);  // low16=bf(f0), high16=bf(f1)
}

// async global->LDS, 16B per lane. lds base wave-uniform; HW adds lane*16.
__device__ __forceinline__ void gl_lds16(const u16* g, const u16* l) {
    __builtin_amdgcn_global_load_lds(
        (const __attribute__((address_space(1))) void*)g,
        (__attribute__((address_space(3))) void*)l,
        16, 0, 0);
}

__device__ __forceinline__ bf16x8 ld_frag(const u16* p) {
    return *(const bf16x8*)p;
}

// ---------------------------------------------------------------------------
// Merged prep: blocks [0,4096) convert x fp32->bf16 (8 elems/thread);
// blocks [4096,5120) transpose+convert W [K,N] fp32 -> Wt [N,K] bf16.
// ---------------------------------------------------------------------------
__global__ void prep_kernel(const float* __restrict__ x, u16* __restrict__ xb,
                            const float* __restrict__ w0, const float* __restrict__ w1,
                            const float* __restrict__ w2, const float* __restrict__ w3,
                            u16* __restrict__ out) {
    __shared__ u16 tile[64][65];
    if (blockIdx.x < 4096) {
        const size_t i = (size_t)blockIdx.x * 256 + threadIdx.x;
        const float4* s = (const float4*)x + i * 2;
        const float4 a = s[0], b = s[1];
        u16 v[8] __attribute__((aligned(16)));
        v[0]=f2bf(a.x); v[1]=f2bf(a.y); v[2]=f2bf(a.z); v[3]=f2bf(a.w);
        v[4]=f2bf(b.x); v[5]=f2bf(b.y); v[6]=f2bf(b.z); v[7]=f2bf(b.w);
        *(uint4*)(xb + i * 8) = *(const uint4*)v;
        return;
    }
    const int bz2 = (int)blockIdx.x - 4096;
    const int z = bz2 >> 8, rem = bz2 & 255, byy = rem >> 4, bxx = rem & 15;
    const float* W = z == 0 ? w0 : z == 1 ? w1 : z == 2 ? w2 : w3;
    u16* O = out + (size_t)z * E2;
    const int k0 = byy * 64, n0 = bxx * 64;
    const int r = threadIdx.x >> 2, cp = (threadIdx.x & 3) * 16;
    const float4* src = (const float4*)&W[(size_t)(k0 + r) * E_DIM + n0 + cp];
    #pragma unroll
    for (int j4 = 0; j4 < 4; ++j4) {
        const float4 f = src[j4];
        tile[r][cp + j4*4 + 0] = f2bf(f.x);
        tile[r][cp + j4*4 + 1] = f2bf(f.y);
        tile[r][cp + j4*4 + 2] = f2bf(f.z);
        tile[r][cp + j4*4 + 3] = f2bf(f.w);
    }
    __syncthreads();
    u16 vals[16] __attribute__((aligned(16)));
    #pragma unroll
    for (int j = 0; j < 16; ++j) vals[j] = tile[cp + j][r];
    u16* dst = &O[(size_t)(n0 + r) * E_DIM + k0 + cp];
    *(uint4*)dst       = *(const uint4*)vals;
    *(uint4*)(dst + 8) = *(const uint4*)(vals + 8);
}

// ---------------------------------------------------------------------------
// bf16 MFMA GEMM (round-4 verified core) + XCD-chunked block remap (T1):
// BK=64, single-buffered 32 KiB LDS, 128x128 tile, 4 waves. Per K-step:
// sync -> stage 8 gl_lds -> sync -> 2 x {read 8 frags, 16 MFMA}.
// Chunk-XOR swizzle slot = c ^ (row&7) on source + ds_read.
// T1 verdict (round 10): FETCH_SIZE 71.8 -> 41.2 MB (-42%, real, same-run);
// duration within cross-run noise (65-69-79 us spread on identical code) ->
// GEMM is barrier-drain-bound, not fetch-bound. Keep T1 (less HBM traffic).
// Round-5 lesson: explicit dbuf cut occupancy 26->19% and regressed — keep
// single-buffered + high TLP.
// ---------------------------------------------------------------------------
template<int REMAP>
__global__ __launch_bounds__(256)
void gemm_bf16_kernel(const u16* __restrict__ A, const u16* __restrict__ Bt,
                      const float* __restrict__ bias0, const float* __restrict__ bias1,
                      const float* __restrict__ bias2, void* __restrict__ outp,
                      u16* __restrict__ vtp)
{
    __shared__ __attribute__((aligned(16))) u16 As[128 * 64];
    __shared__ __attribute__((aligned(16))) u16 Bs[128 * 64];
    const int tid = threadIdx.x;
    const int w = tid >> 6, lane = tid & 63, quad = lane >> 4, l15 = lane & 15;
    const int wm = w >> 1, wn = w & 1;

    // XCD-chunked block remap (dispatch linear id: x fastest)
    const int id = (int)(blockIdx.x + blockIdx.y * gridDim.x);
    const int xcd = id & 7, ord2 = id >> 3;
    int bx, by;
    if (REMAP == 1) {               // 24x64: XCD chunk = 12 cols x 16 rows (2x4)
        const int tcx = xcd & 1, tcy = xcd >> 1;
        bx = tcx * 12 + ord2 % 12;
        by = tcy * 16 + ord2 / 12;
    } else {                        // 8x64: XCD chunk = 8 cols x 8 rows (1x8)
        bx = ord2 & 7;
        by = (xcd << 3) + (ord2 >> 3);
    }
    const int r0 = by * 128, c0 = bx * 128;

    floatx4 acc[4][4];
    #pragma unroll
    for (int mi = 0; mi < 4; ++mi)
        #pragma unroll
        for (int ni = 0; ni < 4; ++ni)
            acc[mi][ni] = (floatx4){0.f, 0.f, 0.f, 0.f};

    // staging source pointers (pre-swizzled chunk): 4 issues each for A, B
    const u16* pA[4]; const u16* pB[4];
    #pragma unroll
    for (int i = 0; i < 4; ++i) {
        const int L = i * 256 + tid, row = L >> 3, s = L & 7, c = s ^ (row & 7);
        pA[i] = A  + (size_t)(r0 + row) * E_DIM + c * 8;
        pB[i] = Bt + (size_t)(c0 + row) * E_DIM + c * 8;
    }

    for (int k0 = 0; k0 < E_DIM; k0 += 64) {
        __syncthreads();
        #pragma unroll
        for (int i = 0; i < 4; ++i) {
            const unsigned off = __builtin_amdgcn_readfirstlane(i * 4096 + w * 1024);
            gl_lds16(pA[i] + k0, (u16*)((char*)As + off));
            gl_lds16(pB[i] + k0, (u16*)((char*)Bs + off));
        }
        __syncthreads();
        #pragma unroll
        for (int kk = 0; kk < 2; ++kk) {
            const int sl = ((kk * 4 + quad) ^ (l15 & 7)) * 8;   // swizzled chunk
            bf16x8 Af[4], Bf[4];
            #pragma unroll
            for (int mi = 0; mi < 4; ++mi) Af[mi] = ld_frag(&As[(wm*64 + mi*16 + l15) * 64 + sl]);
            #pragma unroll
            for (int ni = 0; ni < 4; ++ni) Bf[ni] = ld_frag(&Bs[(wn*64 + ni*16 + l15) * 64 + sl]);
            #pragma unroll
            for (int mi = 0; mi < 4; ++mi)
                #pragma unroll
                for (int ni = 0; ni < 4; ++ni)
                    acc[mi][ni] = __builtin_amdgcn_mfma_f32_16x16x32_bf16(Af[mi], Bf[ni], acc[mi][ni], 0, 0, 0);
        }
    }

    #pragma unroll
    for (int ni = 0; ni < 4; ++ni) {
        const int col = c0 + wn * 64 + ni * 16 + l15;
        float bv;
        int which = 0, cc = col;
        if (REMAP == 1) {
            which = col >> 10; cc = col & 1023;
            const float* bp_ = which == 0 ? bias0 : which == 1 ? bias1 : bias2;
            bv = bp_[cc];
        } else {
            bv = bias0[col];
        }
        #pragma unroll
        for (int mi = 0; mi < 4; ++mi) {
            if (REMAP == 1 && which == 2) {
                // V^T: vt[bh][d][t], 4 consecutive t -> one uint2 store
                const int h = cc >> 6, d = cc & 63;
                const int row0 = r0 + wm * 64 + mi * 16 + quad * 4;
                const int b = row0 >> 11, t0 = row0 & (T_DIM - 1);
                uint2 pk;
                pk.x = pack2bf(acc[mi][ni][0] + bv, acc[mi][ni][1] + bv);
                pk.y = pack2bf(acc[mi][ni][2] + bv, acc[mi][ni][3] + bv);
                *(uint2*)&vtp[((size_t)((b * H_DIM + h) * HD + d)) * T_DIM + t0] = pk;
            } else {
                #pragma unroll
                for (int r = 0; r < 4; ++r) {
                    const int row = r0 + wm * 64 + mi * 16 + quad * 4 + r;
                    float val = acc[mi][ni][r] + bv;
                    if (REMAP == 1) {
                        if (which == 0) val *= QSCALE;
                        const int h = cc >> 6, d = cc & 63;
                        const int b = row >> 11, t = row & (T_DIM - 1);
                        ((u16*)outp)[(size_t)which * NE +
                                     (((size_t)(b * H_DIM + h) * T_DIM + t) * HD + d)] = f2bf(val);
                    } else {
                        ((float*)outp)[(size_t)row * E_DIM + col] = val;
                    }
                }
            }
        }
    }
}

// ---------------------------------------------------------------------------
// MFMA flash attention v8: v6 math (verified) with SINGLE-buffered K/V and
// 4 blocks/CU. Rationale (GEMM rounds 4/5 evidence, applied to attn): v6's
// dbuf used 64 KiB LDS -> 2 blocks/CU, 2 waves/SIMD; every tile-step still
// drains at a barrier. Single buffer (32 KiB) + __launch_bounds__(256,4)
// -> 4 blocks/CU: inter-block TLP hides the now-exposed stage latency
// (stall << 3x compute-phase). L2 locality per bh already ideal (all 16
// q-blocks of a bh land on one XCD: id%8 = bh%8).
// Loop: stage(jt) -> sync (drain) -> compute(jt) -> sync (readers done
// before next overwrite). Two barriers/tile vs one, traded for 2x TLP.
// ---------------------------------------------------------------------------
__global__ __launch_bounds__(256, 4)
void attn_kernel(const u16* __restrict__ q, const u16* __restrict__ k,
                 const u16* __restrict__ vt, u16* __restrict__ y)
{
    __shared__ u16 Ks[128 * 64];   // [key][d], 8 chunks/row, XOR-swizzled
    __shared__ u16 Vs[64 * 128];   // [d][key], 16 chunks/row, swizzled

    const int tid = threadIdx.x;
    const int w = tid >> 6, lane = tid & 63;
    const int hl = lane >> 5, l31 = lane & 31, l7 = lane & 7;
    const int bh = blockIdx.x;                    // XCD = bh % 8
    const int qt = gridDim.y - 1 - blockIdx.y;    // heavy q-blocks dispatch first
    const int q0 = qt * 128;
    const int b = bh >> 4, h = bh & (H_DIM - 1);
    const size_t qkb = (size_t)bh * (T_DIM * HD);
    const size_t vtb = (size_t)bh * (HD * T_DIM);

    // Q as B-operand: lane holds Q[d = kc*16 + hl*8 + j][query = q0+w*32+l31]
    const int qrow = q0 + w * 32 + l31;
    bf16x8 Qf[4];
    #pragma unroll
    for (int kc = 0; kc < 4; ++kc)
        Qf[kc] = ld_frag(&q[qkb + (size_t)qrow * HD + kc * 16 + hl * 8]);

    float rsum = 0.f;                 // row sum for query l31 (half-wave partial)
    floatx16 O[2];
    #pragma unroll
    for (int i = 0; i < 16; ++i) { O[0][i] = 0.f; O[1][i] = 0.f; }

    // stage K/V tile jt into the single buffer (async; drained by next sync)
    auto stage = [&](int jt) {
        const int j0 = jt * 128;
        #pragma unroll
        for (int i = 0; i < 4; ++i) {
            const int L = i * 256 + tid;
            const unsigned off = __builtin_amdgcn_readfirstlane(i * 4096 + w * 1024);
            {   const int row = L >> 3, ch = (L & 7) ^ (row & 7);
                gl_lds16(&k[qkb + (size_t)(j0 + row) * HD + ch * 8],
                         (u16*)((char*)&Ks[0] + off)); }
            {   const int row = L >> 4, ch = (L & 15) ^ (row & 7);
                gl_lds16(&vt[vtb + (size_t)row * T_DIM + j0 + ch * 8],
                         (u16*)((char*)&Vs[0] + off)); }
        }
    };

    for (int jt = 0; jt <= qt; ++jt) {
        stage(jt);
        __syncthreads();                       // drains stage(jt)

        const bool diag = (jt == qt);
        const int nkg = diag ? (w + 1) : 4;    // active 32-key groups

        #pragma unroll
        for (int kg = 0; kg < 4; ++kg) {
            if (kg < nkg) {
                // S^T = K_kg @ Q : D[key=(reg&3)+8*(reg>>2)+4*hl][query=l31]
                floatx16 S;
                #pragma unroll
                for (int i = 0; i < 16; ++i) S[i] = 0.f;
                const int krow = kg * 32 + l31;
                #pragma unroll
                for (int kc = 0; kc < 4; ++kc) {
                    const int ch = (kc * 2 + hl) ^ l7;      // krow&7 == l7
                    S = __builtin_amdgcn_mfma_f32_32x32x16_bf16(
                            ld_frag(&Ks[krow * 64 + ch * 8]), Qf[kc], S, 0, 0, 0);
                }

                // exp2 (+ causal mask on boundary group), rsum, pack
                const bool bnd = diag && (kg == w);
                u32 u[8], ru[8];
                #pragma unroll
                for (int i = 0; i < 8; ++i) {
                    const int row0 = (2*i & 3) + 8 * (i >> 1) + 4 * hl;
                    float p0 = __builtin_amdgcn_exp2f(S[2*i]);
                    float p1 = __builtin_amdgcn_exp2f(S[2*i + 1]);
                    if (bnd && (row0     > l31)) p0 = 0.f;
                    if (bnd && (row0 + 1 > l31)) p1 = 0.f;
                    rsum += p0 + p1;
                    u[i] = pack2bf(p0, p1);
                }
                // lane^32 exchange: build PV A-frags (m=query=l31, k=keys)
                #pragma unroll
                for (int i = 0; i < 8; ++i) ru[i] = __shfl_xor(u[i], 32, 64);
                const u32x4 f0 = hl ? (u32x4){ru[2], ru[3], u[2], u[3]}
                                    : (u32x4){u[0], u[1], ru[0], ru[1]};
                const u32x4 f1 = hl ? (u32x4){ru[6], ru[7], u[6], u[7]}
                                    : (u32x4){u[4], u[5], ru[4], ru[5]};

                // O[dh] += P_chunk @ V  (B: lane = V[key=8*kc16+j][d=dh*32+l31])
                #pragma unroll
                for (int c2 = 0; c2 < 2; ++c2) {
                    const bf16x8 Pf = __builtin_bit_cast(bf16x8, c2 ? f1 : f0);
                    const int kc16 = kg * 4 + c2 * 2 + hl;
                    #pragma unroll
                    for (int dh = 0; dh < 2; ++dh) {
                        const int d = dh * 32 + l31;
                        const int ch = kc16 ^ l7;           // d&7 == l7
                        O[dh] = __builtin_amdgcn_mfma_f32_32x32x16_bf16(
                                    Pf, ld_frag(&Vs[d * 128 + ch * 8]), O[dh], 0, 0, 0);
                    }
                }
            }
        }
        if (jt < qt) __syncthreads();          // readers done before overwrite
    }

    // epilogue: complete row sums (halves), normalize, store merged heads
    rsum += __shfl_xor(rsum, 32, 64);
    const float linv = 1.0f / rsum;            // for query l31
    #pragma unroll
    for (int i = 0; i < 16; ++i) {
        const int qr = (i & 3) + 8 * (i >> 2) + 4 * hl;    // query row of reg i
        const float lq = __shfl(linv, qr, 32);
        const int t = q0 + w * 32 + qr;
        const size_t base = ((size_t)(b * T_DIM + t)) * E_DIM + h * HD;
        y[base + l31]      = f2bf(O[0][i] * lq);
        y[base + 32 + l31] = f2bf(O[1][i] * lq);
    }
}

extern "C" void kernel_launch(void* const* d_in, const int* in_sizes, int n_in,
                              void* d_out, int out_size, void* d_ws, size_t ws_size,
                              hipStream_t stream)
{
    const float* x  = (const float*)d_in[0];
    const float* Wq = (const float*)d_in[2];
    const float* bq = (const float*)d_in[3];
    const float* Wk = (const float*)d_in[4];
    const float* bk = (const float*)d_in[5];
    const float* Wv = (const float*)d_in[6];
    const float* bv = (const float*)d_in[7];
    const float* Wp = (const float*)d_in[8];
    const float* bp = (const float*)d_in[9];

    u16* xb  = (u16*)d_ws;          // NE
    u16* wt  = xb + NE;             // 4*E2
    u16* qb  = wt + 4 * (size_t)E2; // NE (q) ; k at qb+NE
    u16* kb  = qb + NE;             // NE
    u16* vtb = kb + NE;             // NE  (V^T, written by the QKV GEMM)
    u16* yb  = vtb + NE;            // NE

    prep_kernel<<<5120, 256, 0, stream>>>(x, xb, Wq, Wk, Wv, Wp, wt);
    gemm_bf16_kernel<1><<<dim3(24, 64), 256, 0, stream>>>(xb, wt, bq, bk, bv, qb, vtb);
    attn_kernel<<<dim3(64, 16), 256, 0, stream>>>(qb, kb, vtb, yb);
    gemm_bf16_kernel<0><<<dim3(8, 64), 256, 0, stream>>>(yb, wt + 3 * (size_t)E2, bp, bp, bp, (float*)d_out, nullptr);
}

// Round 13
// 243.983 us; speedup vs baseline: 1.2059x; 1.2059x over previous
//
#include <hip/hip_runtime.h>
#include <cmath>

typedef unsigned short u16;
typedef unsigned int u32;
typedef __bf16 bf16x8 __attribute__((ext_vector_type(8)));
typedef float  floatx4 __attribute__((ext_vector_type(4)));
typedef float  floatx16 __attribute__((ext_vector_type(16)));
typedef unsigned int u32x4 __attribute__((ext_vector_type(4)));

#define T_DIM 2048
#define E_DIM 1024
#define H_DIM 16
#define HD    64
#define M_DIM 8192                    // B*T
#define NE    8388608                 // M*E  (also B*H*T*HD)
#define E2    1048576                 // E*E
#define QSCALE 0.18033688f            // 0.125 * log2(e): logits in exp2 domain

// float -> bf16 (RNE)
__device__ __forceinline__ u16 f2bf(float f) {
    unsigned u = __builtin_bit_cast(unsigned, f);
    return (u16)((u + 0x7FFFu + ((u >> 16) & 1u)) >> 16);
}
// two floats -> packed bf16x2 (proven numerics)
__device__ __forceinline__ u32 pack2bf(float f0, float f1) {
    u32 a0 = __builtin_bit_cast(u32, f0) + 0x8000u;
    u32 a1 = __builtin_bit_cast(u32, f1) + 0x8000u;
    return __builtin_amdgcn_perm(a1, a0, 0x07060302u);  // low16=bf(f0), high16=bf(f1)
}

// async global->LDS, 16B per lane. lds base wave-uniform; HW adds lane*16.
__device__ __forceinline__ void gl_lds16(const u16* g, const u16* l) {
    __builtin_amdgcn_global_load_lds(
        (const __attribute__((address_space(1))) void*)g,
        (__attribute__((address_space(3))) void*)l,
        16, 0, 0);
}

__device__ __forceinline__ bf16x8 ld_frag(const u16* p) {
    return *(const bf16x8*)p;
}

// ---------------------------------------------------------------------------
// Merged prep: blocks [0,4096) convert x fp32->bf16 (8 elems/thread);
// blocks [4096,5120) transpose+convert W [K,N] fp32 -> Wt [N,K] bf16.
// ---------------------------------------------------------------------------
__global__ void prep_kernel(const float* __restrict__ x, u16* __restrict__ xb,
                            const float* __restrict__ w0, const float* __restrict__ w1,
                            const float* __restrict__ w2, const float* __restrict__ w3,
                            u16* __restrict__ out) {
    __shared__ u16 tile[64][65];
    if (blockIdx.x < 4096) {
        const size_t i = (size_t)blockIdx.x * 256 + threadIdx.x;
        const float4* s = (const float4*)x + i * 2;
        const float4 a = s[0], b = s[1];
        u16 v[8] __attribute__((aligned(16)));
        v[0]=f2bf(a.x); v[1]=f2bf(a.y); v[2]=f2bf(a.z); v[3]=f2bf(a.w);
        v[4]=f2bf(b.x); v[5]=f2bf(b.y); v[6]=f2bf(b.z); v[7]=f2bf(b.w);
        *(uint4*)(xb + i * 8) = *(const uint4*)v;
        return;
    }
    const int bz2 = (int)blockIdx.x - 4096;
    const int z = bz2 >> 8, rem = bz2 & 255, byy = rem >> 4, bxx = rem & 15;
    const float* W = z == 0 ? w0 : z == 1 ? w1 : z == 2 ? w2 : w3;
    u16* O = out + (size_t)z * E2;
    const int k0 = byy * 64, n0 = bxx * 64;
    const int r = threadIdx.x >> 2, cp = (threadIdx.x & 3) * 16;
    const float4* src = (const float4*)&W[(size_t)(k0 + r) * E_DIM + n0 + cp];
    #pragma unroll
    for (int j4 = 0; j4 < 4; ++j4) {
        const float4 f = src[j4];
        tile[r][cp + j4*4 + 0] = f2bf(f.x);
        tile[r][cp + j4*4 + 1] = f2bf(f.y);
        tile[r][cp + j4*4 + 2] = f2bf(f.z);
        tile[r][cp + j4*4 + 3] = f2bf(f.w);
    }
    __syncthreads();
    u16 vals[16] __attribute__((aligned(16)));
    #pragma unroll
    for (int j = 0; j < 16; ++j) vals[j] = tile[cp + j][r];
    u16* dst = &O[(size_t)(n0 + r) * E_DIM + k0 + cp];
    *(uint4*)dst       = *(const uint4*)vals;
    *(uint4*)(dst + 8) = *(const uint4*)(vals + 8);
}

// ---------------------------------------------------------------------------
// bf16 MFMA GEMM (round-4 verified core) + XCD-chunked block remap (T1):
// BK=64, single-buffered 32 KiB LDS, 128x128 tile, 4 waves. Per K-step:
// sync -> stage 8 gl_lds -> sync -> 2 x {read 8 frags, 16 MFMA}.
// Chunk-XOR swizzle slot = c ^ (row&7) on source + ds_read.
// T1 verdict (round 10): FETCH_SIZE 71.8 -> 41.2 MB (-42%, real, same-run);
// duration within cross-run noise -> GEMM is barrier-drain-bound, not
// fetch-bound. Keep T1 (less HBM traffic). Round-5 lesson: explicit dbuf
// cut occupancy 26->19% and regressed — keep single-buffered + high TLP.
// ---------------------------------------------------------------------------
template<int REMAP>
__global__ __launch_bounds__(256)
void gemm_bf16_kernel(const u16* __restrict__ A, const u16* __restrict__ Bt,
                      const float* __restrict__ bias0, const float* __restrict__ bias1,
                      const float* __restrict__ bias2, void* __restrict__ outp,
                      u16* __restrict__ vtp)
{
    __shared__ __attribute__((aligned(16))) u16 As[128 * 64];
    __shared__ __attribute__((aligned(16))) u16 Bs[128 * 64];
    const int tid = threadIdx.x;
    const int w = tid >> 6, lane = tid & 63, quad = lane >> 4, l15 = lane & 15;
    const int wm = w >> 1, wn = w & 1;

    // XCD-chunked block remap (dispatch linear id: x fastest)
    const int id = (int)(blockIdx.x + blockIdx.y * gridDim.x);
    const int xcd = id & 7, ord2 = id >> 3;
    int bx, by;
    if (REMAP == 1) {               // 24x64: XCD chunk = 12 cols x 16 rows (2x4)
        const int tcx = xcd & 1, tcy = xcd >> 1;
        bx = tcx * 12 + ord2 % 12;
        by = tcy * 16 + ord2 / 12;
    } else {                        // 8x64: XCD chunk = 8 cols x 8 rows (1x8)
        bx = ord2 & 7;
        by = (xcd << 3) + (ord2 >> 3);
    }
    const int r0 = by * 128, c0 = bx * 128;

    floatx4 acc[4][4];
    #pragma unroll
    for (int mi = 0; mi < 4; ++mi)
        #pragma unroll
        for (int ni = 0; ni < 4; ++ni)
            acc[mi][ni] = (floatx4){0.f, 0.f, 0.f, 0.f};

    // staging source pointers (pre-swizzled chunk): 4 issues each for A, B
    const u16* pA[4]; const u16* pB[4];
    #pragma unroll
    for (int i = 0; i < 4; ++i) {
        const int L = i * 256 + tid, row = L >> 3, s = L & 7, c = s ^ (row & 7);
        pA[i] = A  + (size_t)(r0 + row) * E_DIM + c * 8;
        pB[i] = Bt + (size_t)(c0 + row) * E_DIM + c * 8;
    }

    for (int k0 = 0; k0 < E_DIM; k0 += 64) {
        __syncthreads();
        #pragma unroll
        for (int i = 0; i < 4; ++i) {
            const unsigned off = __builtin_amdgcn_readfirstlane(i * 4096 + w * 1024);
            gl_lds16(pA[i] + k0, (u16*)((char*)As + off));
            gl_lds16(pB[i] + k0, (u16*)((char*)Bs + off));
        }
        __syncthreads();
        #pragma unroll
        for (int kk = 0; kk < 2; ++kk) {
            const int sl = ((kk * 4 + quad) ^ (l15 & 7)) * 8;   // swizzled chunk
            bf16x8 Af[4], Bf[4];
            #pragma unroll
            for (int mi = 0; mi < 4; ++mi) Af[mi] = ld_frag(&As[(wm*64 + mi*16 + l15) * 64 + sl]);
            #pragma unroll
            for (int ni = 0; ni < 4; ++ni) Bf[ni] = ld_frag(&Bs[(wn*64 + ni*16 + l15) * 64 + sl]);
            #pragma unroll
            for (int mi = 0; mi < 4; ++mi)
                #pragma unroll
                for (int ni = 0; ni < 4; ++ni)
                    acc[mi][ni] = __builtin_amdgcn_mfma_f32_16x16x32_bf16(Af[mi], Bf[ni], acc[mi][ni], 0, 0, 0);
        }
    }

    #pragma unroll
    for (int ni = 0; ni < 4; ++ni) {
        const int col = c0 + wn * 64 + ni * 16 + l15;
        float bv;
        int which = 0, cc = col;
        if (REMAP == 1) {
            which = col >> 10; cc = col & 1023;
            const float* bp_ = which == 0 ? bias0 : which == 1 ? bias1 : bias2;
            bv = bp_[cc];
        } else {
            bv = bias0[col];
        }
        #pragma unroll
        for (int mi = 0; mi < 4; ++mi) {
            if (REMAP == 1 && which == 2) {
                // V^T: vt[bh][d][t], 4 consecutive t -> one uint2 store
                const int h = cc >> 6, d = cc & 63;
                const int row0 = r0 + wm * 64 + mi * 16 + quad * 4;
                const int b = row0 >> 11, t0 = row0 & (T_DIM - 1);
                uint2 pk;
                pk.x = pack2bf(acc[mi][ni][0] + bv, acc[mi][ni][1] + bv);
                pk.y = pack2bf(acc[mi][ni][2] + bv, acc[mi][ni][3] + bv);
                *(uint2*)&vtp[((size_t)((b * H_DIM + h) * HD + d)) * T_DIM + t0] = pk;
            } else {
                #pragma unroll
                for (int r = 0; r < 4; ++r) {
                    const int row = r0 + wm * 64 + mi * 16 + quad * 4 + r;
                    float val = acc[mi][ni][r] + bv;
                    if (REMAP == 1) {
                        if (which == 0) val *= QSCALE;
                        const int h = cc >> 6, d = cc & 63;
                        const int b = row >> 11, t = row & (T_DIM - 1);
                        ((u16*)outp)[(size_t)which * NE +
                                     (((size_t)(b * H_DIM + h) * T_DIM + t) * HD + d)] = f2bf(val);
                    } else {
                        ((float*)outp)[(size_t)row * E_DIM + col] = val;
                    }
                }
            }
        }
    }
}

// ---------------------------------------------------------------------------
// MFMA flash attention v6 (verified, FINAL): 32x32x16 MFMA, no P LDS
// round-trip (lane^32 exchange), max-free softmax, double-buffered K/V
// staging with XOR swizzles, 2 blocks/CU.
// Round-12 lesson: forcing 4 blocks/CU (single buffer + launch_bounds(256,4))
// capped VGPR at 64 -> spills + 4.3M bank conflicts -> 105 us (vs ~60).
// Attn's ~48-reg live accumulator state makes >2 waves/SIMD unreachable;
// G6 (register pressure) dominates G1 (occupancy) here. Keep dbuf.
// ---------------------------------------------------------------------------
__global__ __launch_bounds__(256, 2)
void attn_kernel(const u16* __restrict__ q, const u16* __restrict__ k,
                 const u16* __restrict__ vt, u16* __restrict__ y)
{
    __shared__ u16 Ks[2][128 * 64];   // [key][d], 8 chunks/row, XOR-swizzled
    __shared__ u16 Vs[2][64 * 128];   // [d][key], 16 chunks/row, swizzled

    const int tid = threadIdx.x;
    const int w = tid >> 6, lane = tid & 63;
    const int hl = lane >> 5, l31 = lane & 31, l7 = lane & 7;
    const int bh = blockIdx.x;                    // XCD = bh % 8
    const int qt = gridDim.y - 1 - blockIdx.y;    // heavy q-blocks dispatch first
    const int q0 = qt * 128;
    const int b = bh >> 4, h = bh & (H_DIM - 1);
    const size_t qkb = (size_t)bh * (T_DIM * HD);
    const size_t vtb = (size_t)bh * (HD * T_DIM);

    // Q as B-operand: lane holds Q[d = kc*16 + hl*8 + j][query = q0+w*32+l31]
    const int qrow = q0 + w * 32 + l31;
    bf16x8 Qf[4];
    #pragma unroll
    for (int kc = 0; kc < 4; ++kc)
        Qf[kc] = ld_frag(&q[qkb + (size_t)qrow * HD + kc * 16 + hl * 8]);

    float rsum = 0.f;                 // row sum for query l31 (half-wave partial)
    floatx16 O[2];
    #pragma unroll
    for (int i = 0; i < 16; ++i) { O[0][i] = 0.f; O[1][i] = 0.f; }

    // stage K/V tile jt into buffer sel (async; fenced by next __syncthreads)
    auto stage = [&](int jt, int sel) {
        const int j0 = jt * 128;
        #pragma unroll
        for (int i = 0; i < 4; ++i) {
            const int L = i * 256 + tid;
            const unsigned off = __builtin_amdgcn_readfirstlane(i * 4096 + w * 1024);
            {   const int row = L >> 3, ch = (L & 7) ^ (row & 7);
                gl_lds16(&k[qkb + (size_t)(j0 + row) * HD + ch * 8],
                         (u16*)((char*)&Ks[sel][0] + off)); }
            {   const int row = L >> 4, ch = (L & 15) ^ (row & 7);
                gl_lds16(&vt[vtb + (size_t)row * T_DIM + j0 + ch * 8],
                         (u16*)((char*)&Vs[sel][0] + off)); }
        }
    };

    stage(0, 0);
    for (int jt = 0; jt <= qt; ++jt) {
        __syncthreads();                       // drains stage(jt)
        if (jt < qt) stage(jt + 1, (jt + 1) & 1);
        const u16* const Kb = &Ks[jt & 1][0];
        const u16* const Vb = &Vs[jt & 1][0];

        const bool diag = (jt == qt);
        const int nkg = diag ? (w + 1) : 4;    // active 32-key groups

        #pragma unroll
        for (int kg = 0; kg < 4; ++kg) {
            if (kg < nkg) {
                // S^T = K_kg @ Q : D[key=(reg&3)+8*(reg>>2)+4*hl][query=l31]
                floatx16 S;
                #pragma unroll
                for (int i = 0; i < 16; ++i) S[i] = 0.f;
                const int krow = kg * 32 + l31;
                #pragma unroll
                for (int kc = 0; kc < 4; ++kc) {
                    const int ch = (kc * 2 + hl) ^ l7;      // krow&7 == l7
                    S = __builtin_amdgcn_mfma_f32_32x32x16_bf16(
                            ld_frag(&Kb[krow * 64 + ch * 8]), Qf[kc], S, 0, 0, 0);
                }

                // exp2 (+ causal mask on boundary group), rsum, pack
                const bool bnd = diag && (kg == w);
                u32 u[8], ru[8];
                #pragma unroll
                for (int i = 0; i < 8; ++i) {
                    const int row0 = (2*i & 3) + 8 * (i >> 1) + 4 * hl;
                    float p0 = __builtin_amdgcn_exp2f(S[2*i]);
                    float p1 = __builtin_amdgcn_exp2f(S[2*i + 1]);
                    if (bnd && (row0     > l31)) p0 = 0.f;
                    if (bnd && (row0 + 1 > l31)) p1 = 0.f;
                    rsum += p0 + p1;
                    u[i] = pack2bf(p0, p1);
                }
                // lane^32 exchange: build PV A-frags (m=query=l31, k=keys)
                #pragma unroll
                for (int i = 0; i < 8; ++i) ru[i] = __shfl_xor(u[i], 32, 64);
                const u32x4 f0 = hl ? (u32x4){ru[2], ru[3], u[2], u[3]}
                                    : (u32x4){u[0], u[1], ru[0], ru[1]};
                const u32x4 f1 = hl ? (u32x4){ru[6], ru[7], u[6], u[7]}
                                    : (u32x4){u[4], u[5], ru[4], ru[5]};

                // O[dh] += P_chunk @ V  (B: lane = V[key=8*kc16+j][d=dh*32+l31])
                #pragma unroll
                for (int c2 = 0; c2 < 2; ++c2) {
                    const bf16x8 Pf = __builtin_bit_cast(bf16x8, c2 ? f1 : f0);
                    const int kc16 = kg * 4 + c2 * 2 + hl;
                    #pragma unroll
                    for (int dh = 0; dh < 2; ++dh) {
                        const int d = dh * 32 + l31;
                        const int ch = kc16 ^ l7;           // d&7 == l7
                        O[dh] = __builtin_amdgcn_mfma_f32_32x32x16_bf16(
                                    Pf, ld_frag(&Vb[d * 128 + ch * 8]), O[dh], 0, 0, 0);
                    }
                }
            }
        }
    }

    // epilogue: complete row sums (halves), normalize, store merged heads
    rsum += __shfl_xor(rsum, 32, 64);
    const float linv = 1.0f / rsum;            // for query l31
    #pragma unroll
    for (int i = 0; i < 16; ++i) {
        const int qr = (i & 3) + 8 * (i >> 2) + 4 * hl;    // query row of reg i
        const float lq = __shfl(linv, qr, 32);
        const int t = q0 + w * 32 + qr;
        const size_t base = ((size_t)(b * T_DIM + t)) * E_DIM + h * HD;
        y[base + l31]      = f2bf(O[0][i] * lq);
        y[base + 32 + l31] = f2bf(O[1][i] * lq);
    }
}

extern "C" void kernel_launch(void* const* d_in, const int* in_sizes, int n_in,
                              void* d_out, int out_size, void* d_ws, size_t ws_size,
                              hipStream_t stream)
{
    const float* x  = (const float*)d_in[0];
    const float* Wq = (const float*)d_in[2];
    const float* bq = (const float*)d_in[3];
    const float* Wk = (const float*)d_in[4];
    const float* bk = (const float*)d_in[5];
    const float* Wv = (const float*)d_in[6];
    const float* bv = (const float*)d_in[7];
    const float* Wp = (const float*)d_in[8];
    const float* bp = (const float*)d_in[9];

    u16* xb  = (u16*)d_ws;          // NE
    u16* wt  = xb + NE;             // 4*E2
    u16* qb  = wt + 4 * (size_t)E2; // NE (q) ; k at qb+NE
    u16* kb  = qb + NE;             // NE
    u16* vtb = kb + NE;             // NE  (V^T, written by the QKV GEMM)
    u16* yb  = vtb + NE;            // NE

    prep_kernel<<<5120, 256, 0, stream>>>(x, xb, Wq, Wk, Wv, Wp, wt);
    gemm_bf16_kernel<1><<<dim3(24, 64), 256, 0, stream>>>(xb, wt, bq, bk, bv, qb, vtb);
    attn_kernel<<<dim3(64, 16), 256, 0, stream>>>(qb, kb, vtb, yb);
    gemm_bf16_kernel<0><<<dim3(8, 64), 256, 0, stream>>>(yb, wt + 3 * (size_t)E2, bp, bp, bp, (float*)d_out, nullptr);
}